// Round 11
// baseline (171.223 us; speedup 1.0000x reference)
//
#include <hip/hip_runtime.h>

typedef _Float16 f16;
typedef __attribute__((ext_vector_type(8))) _Float16 half8;
typedef __attribute__((ext_vector_type(4))) _Float16 half4;
typedef __attribute__((ext_vector_type(2))) _Float16 half2v;
typedef __attribute__((ext_vector_type(4))) float f32x4;
typedef __attribute__((ext_vector_type(16))) float f32x16;
typedef __attribute__((ext_vector_type(4))) unsigned u32x4;

#define S_LEN 4096
#define HID   768
#define NH    12
#define HD    64

#define EXP2(x) __builtin_amdgcn_exp2f(x)
#define PKRTZ_U(a, b) __builtin_bit_cast(unsigned, __builtin_amdgcn_cvt_pkrtz((a), (b)))

__device__ inline void lane32swap(unsigned &x, unsigned &y) {
#if __has_builtin(__builtin_amdgcn_permlane32_swap)
  auto r = __builtin_amdgcn_permlane32_swap((int)x, (int)y, false, false);
  x = (unsigned)r[0];
  y = (unsigned)r[1];
#else
  unsigned px = (unsigned)__shfl_xor((int)x, 32, 64);
  unsigned py = (unsigned)__shfl_xor((int)y, 32, 64);
  bool hi = (threadIdx.x & 32) != 0;
  unsigned nx = hi ? py : x;
  unsigned ny = hi ? y : px;
  x = nx; y = ny;
#endif
}

// ---------------- convert hidden_states f32 -> f16 ----------------
__global__ __launch_bounds__(256) void k_convert_x(const float* __restrict__ x,
                                                   f16* __restrict__ xb) {
  int i = blockIdx.x * 256 + threadIdx.x;
  float4 v = ((const float4*)x)[i];
  half4 h;
  h[0] = (f16)v.x; h[1] = (f16)v.y; h[2] = (f16)v.z; h[3] = (f16)v.w;
  *(half4*)&xb[(size_t)i * 4] = h;
}

// ---------------- mask * log2(e) precompute ----------------
__global__ __launch_bounds__(256) void k_maskcvt(const float* __restrict__ m,
                                                 float* __restrict__ m2) {
  int i = blockIdx.x * 256 + threadIdx.x;
  const float LOG2E = 1.4426950408889634f;
  float4 v = ((const float4*)m)[i];
  ((float4*)m2)[i] = make_float4(v.x * LOG2E, v.y * LOG2E, v.z * LOG2E, v.w * LOG2E);
}

// ---------------- transpose W [K,N] -> wt [N,K], f32 -> f16 ----------------
__global__ __launch_bounds__(256) void k_transw(const float* __restrict__ Wq,
                                                const float* __restrict__ Wk,
                                                const float* __restrict__ Wv,
                                                f16* __restrict__ wtb) {
  __shared__ float tile[32][33];
  const float* W = (blockIdx.z == 0) ? Wq : (blockIdx.z == 1 ? Wk : Wv);
  f16* wt = wtb + (size_t)blockIdx.z * HID * HID;
  int k0 = blockIdx.y * 32, n0 = blockIdx.x * 32;
  int tx = threadIdx.x, ty = threadIdx.y;
  #pragma unroll
  for (int j = ty; j < 32; j += 8)
    tile[j][tx] = W[(size_t)(k0 + j) * HID + n0 + tx];
  __syncthreads();
  #pragma unroll
  for (int j = ty; j < 32; j += 8)
    wt[(size_t)(n0 + j) * HID + k0 + tx] = (f16)tile[tx][j];
}

// ---------------- QKV projection GEMM (m97-style, 128x128 tile) ----------------
__global__ __launch_bounds__(256) void k_gemm_qkv(const f16* __restrict__ xb,
                                                  const f16* __restrict__ wtb,
                                                  const float* __restrict__ bq,
                                                  const float* __restrict__ bk,
                                                  const float* __restrict__ bv,
                                                  f16* __restrict__ qo,
                                                  f16* __restrict__ ko,
                                                  f16* __restrict__ vto) {
  __shared__ __align__(16) f16 As[128 * 32];
  __shared__ __align__(16) f16 Bs[128 * 32];
  const int z = blockIdx.z;
  const f16* wt = wtb + (size_t)z * HID * HID;
  const float* bias = (z == 0) ? bq : (z == 1 ? bk : bv);
  const int brow = blockIdx.y * 128;
  const int bcol = blockIdx.x * 128;
  const int tid = threadIdx.x, wid = tid >> 6, lane = tid & 63;
  const int wr = wid >> 1, wc = wid & 1;
  const int lrow = lane & 15, lk8 = (lane >> 4) * 8;
  const int srow = lane >> 2;
  const int scol = (lane & 3) * 8;

  f32x4 acc[4][4] = {};

  for (int kt = 0; kt < HID; kt += 32) {
    #pragma unroll
    for (int r = 0; r < 2; r++) {
      int row = (wid * 2 + r) * 16 + srow;
      const f16* ga = xb + (size_t)(brow + row) * HID + kt + scol;
      const f16* gb = wt + (size_t)(bcol + row) * HID + kt + scol;
      __builtin_amdgcn_global_load_lds(
          (const __attribute__((address_space(1))) void*)ga,
          (__attribute__((address_space(3))) void*)(As + (wid * 2 + r) * 512),
          16, 0, 0);
      __builtin_amdgcn_global_load_lds(
          (const __attribute__((address_space(1))) void*)gb,
          (__attribute__((address_space(3))) void*)(Bs + (wid * 2 + r) * 512),
          16, 0, 0);
    }
    __syncthreads();

    half8 a[4], b[4];
    #pragma unroll
    for (int m = 0; m < 4; m++)
      a[m] = *(const half8*)&As[(wr * 64 + m * 16 + lrow) * 32 + lk8];
    #pragma unroll
    for (int n = 0; n < 4; n++)
      b[n] = *(const half8*)&Bs[(wc * 64 + n * 16 + lrow) * 32 + lk8];
    #pragma unroll
    for (int m = 0; m < 4; m++)
      #pragma unroll
      for (int n = 0; n < 4; n++)
        acc[m][n] = __builtin_amdgcn_mfma_f32_16x16x32_f16(a[m], b[n], acc[m][n], 0, 0, 0);
    __syncthreads();
  }

  #pragma unroll
  for (int m = 0; m < 4; m++) {
    int row0 = brow + wr * 64 + m * 16 + (lane >> 4) * 4;
    #pragma unroll
    for (int n = 0; n < 4; n++) {
      int col = bcol + wc * 64 + n * 16 + lrow;
      float bsv = bias[col];
      int h = col >> 6, d = col & 63;
      #pragma unroll
      for (int i = 0; i < 4; i++) {
        f16 v = (f16)(acc[m][n][i] + bsv);
        int r2 = row0 + i;
        if (z == 2)      vto[(size_t)(h * HD + d) * S_LEN + r2] = v;
        else if (z == 1) ko[((size_t)h * S_LEN + r2) * HD + d] = v;
        else             qo[((size_t)h * S_LEN + r2) * HD + d] = v;
      }
    }
  }
}

// ---------------- flash attention: 32x32 MFMA, LDS K+V, in-reg P, parity ------
// 512 thr = 8 waves: qset=wid>>1 (4 x 32 q = 128 q/block), par=wid&1 splits
// k-tiles. K,V staged to LDS (gload_lds w=16, XOR-swizzled source), buffer
// indexed by parity; read-frags-to-regs -> barrier -> restage pattern.
// Swapped QK^T (mfma(K,Q)); per-lane softmax (1 shfl); P -> PV B-frags via
// cvt_pkrtz + permlane32_swap (no P LDS). Parity merge via LDS at end.
__global__ __launch_bounds__(512) void k_attn(const f16* __restrict__ qb,
                                              const f16* __restrict__ kb,
                                              const f16* __restrict__ vt,
                                              const float* __restrict__ mask2,
                                              float* __restrict__ dsto,
                                              float* __restrict__ ml,
                                              int nkt, int direct) {
  __shared__ __align__(16) f16 KV[4][64 * 64];   // [0,1]=K par0/1, [2,3]=V par0/1
  __shared__ float cml[4][2][64];
  const int h = blockIdx.y, z = blockIdx.z;
  const int tid = threadIdx.x, wid = tid >> 6, lane = tid & 63;
  const int q31 = lane & 31, lh = lane >> 5;
  const int qset = wid >> 1, par = wid & 1;
  const int qrow0 = blockIdx.x * 128 + qset * 32;
  const size_t hqk = (size_t)h * (S_LEN * HD);
  const int ktbase = z * nkt * 2 * 64;
  const float scale2 = 0.125f * 1.4426950408889634f;

  // Q B-frags [16kd x 32q]: col q=lane&31, kd = kdc*16 + lh*8 + j
  half8 aq[4];
  #pragma unroll
  for (int kdc = 0; kdc < 4; kdc++)
    aq[kdc] = *(const half8*)&qb[hqk + (size_t)(qrow0 + q31) * HD + kdc * 16 + lh * 8];

  // staging geometry: 512 threads x 16B = one 8 KB tile per issue
  const int srow = tid >> 3, sc = tid & 7;
  const int scolS = ((sc ^ (srow & 7)) << 3);

  auto stageK = [&](int b, int kt) {
    const f16* g = kb + hqk + (size_t)(kt + srow) * HD + scolS;
    __builtin_amdgcn_global_load_lds(
        (const __attribute__((address_space(1))) void*)g,
        (__attribute__((address_space(3))) void*)&KV[b][tid << 3], 16, 0, 0);
  };
  auto stageV = [&](int b, int kt) {
    const f16* g = vt + ((size_t)(h * HD + srow)) * S_LEN + kt + scolS;
    __builtin_amdgcn_global_load_lds(
        (const __attribute__((address_space(1))) void*)g,
        (__attribute__((address_space(3))) void*)&KV[2 + b][tid << 3], 16, 0, 0);
  };

  f32x16 acc0 = {}, acc1 = {};
  float mi = -INFINITY, li = 0.f;

  stageK(0, ktbase); stageK(1, ktbase + 64);
  stageV(0, ktbase); stageV(1, ktbase + 64);
  __syncthreads();

  for (int d = 0; d < nkt; ++d) {
    const int kt = ktbase + (2 * d + par) * 64;

    // ---- K frags (own parity buf) -> regs ----
    half8 kf[2][4];
    #pragma unroll
    for (int T = 0; T < 2; T++)
      #pragma unroll
      for (int kdc = 0; kdc < 4; kdc++)
        kf[T][kdc] = *(const half8*)&KV[par][(T * 32 + q31) * 64 +
                                             (((kdc * 2 + lh) ^ (q31 & 7)) << 3)];

    // ---- QK^T swapped: s[T]=S^T[32k x 32q], k-row=(reg&3)+8*(reg>>2)+4*lh ----
    f32x16 s0 = {}, s1 = {};
    __builtin_amdgcn_s_setprio(1);
    #pragma unroll
    for (int kdc = 0; kdc < 4; kdc++)
      s0 = __builtin_amdgcn_mfma_f32_32x32x16_f16(kf[0][kdc], aq[kdc], s0, 0, 0, 0);
    #pragma unroll
    for (int kdc = 0; kdc < 4; kdc++)
      s1 = __builtin_amdgcn_mfma_f32_32x32x16_f16(kf[1][kdc], aq[kdc], s1, 0, 0, 0);
    __builtin_amdgcn_s_setprio(0);

    // ---- V frags (own parity buf) -> regs (kf dead after QK^T) ----
    half8 vf[2][4];
    #pragma unroll
    for (int dt = 0; dt < 2; dt++)
      #pragma unroll
      for (int kc = 0; kc < 4; kc++)
        vf[dt][kc] = *(const half8*)&KV[2 + par][(dt * 32 + q31) * 64 +
                                                 (((kc * 2 + lh) ^ (q31 & 7)) << 3)];
    __syncthreads();   // all waves done reading K,V bufs

    if (d + 1 < nkt) {   // overwrite with next tile pair (lands by end barrier)
      stageK(0, ktbase + (2 * d + 2) * 64); stageK(1, ktbase + (2 * d + 3) * 64);
      stageV(0, ktbase + (2 * d + 2) * 64); stageV(1, ktbase + (2 * d + 3) * 64);
    }

    // ---- scale + premultiplied mask (log2 domain) ----
    #pragma unroll
    for (int m = 0; m < 4; m++) {
      float4 mk0 = *(const float4*)&mask2[kt + 8 * m + 4 * lh];
      float4 mk1 = *(const float4*)&mask2[kt + 32 + 8 * m + 4 * lh];
      s0[4 * m + 0] = s0[4 * m + 0] * scale2 + mk0.x;
      s0[4 * m + 1] = s0[4 * m + 1] * scale2 + mk0.y;
      s0[4 * m + 2] = s0[4 * m + 2] * scale2 + mk0.z;
      s0[4 * m + 3] = s0[4 * m + 3] * scale2 + mk0.w;
      s1[4 * m + 0] = s1[4 * m + 0] * scale2 + mk1.x;
      s1[4 * m + 1] = s1[4 * m + 1] * scale2 + mk1.y;
      s1[4 * m + 2] = s1[4 * m + 2] * scale2 + mk1.z;
      s1[4 * m + 3] = s1[4 * m + 3] * scale2 + mk1.w;
    }
    // ---- max over 32 local + partner (1 shfl) ----
    float mloc = fmaxf(s0[0], s0[1]);
    #pragma unroll
    for (int i = 2; i < 16; i++) mloc = fmaxf(mloc, s0[i]);
    #pragma unroll
    for (int i = 0; i < 16; i++) mloc = fmaxf(mloc, s1[i]);
    mloc = fmaxf(mloc, __shfl_xor(mloc, 32, 64));

    // ---- defer-max (T13, THR=8 -> P <= 256, f16-safe) ----
    float al = 1.f;
    if (!__all(mloc <= mi + 8.f)) {
      const float mn = fmaxf(mi, mloc);
      al = EXP2(mi - mn);
      mi = mn;
      #pragma unroll
      for (int i = 0; i < 16; i++) { acc0[i] *= al; acc1[i] *= al; }
    }
    float rs = 0.f;
    #pragma unroll
    for (int i = 0; i < 16; i++) { s0[i] = EXP2(s0[i] - mi); rs += s0[i]; }
    #pragma unroll
    for (int i = 0; i < 16; i++) { s1[i] = EXP2(s1[i] - mi); rs += s1[i]; }
    rs += __shfl_xor(rs, 32, 64);
    li = li * al + rs;

    // ---- P -> B-frags in-register: cvt_pkrtz + permlane32 swaps (R7-verified) --
    half8 pf[4];
    #pragma unroll
    for (int T = 0; T < 2; T++) {
      unsigned a0[4], a1[4];
      #pragma unroll
      for (int m = 0; m < 4; m++) {
        if (T == 0) {
          a0[m] = PKRTZ_U(s0[4 * m + 0], s0[4 * m + 1]);
          a1[m] = PKRTZ_U(s0[4 * m + 2], s0[4 * m + 3]);
        } else {
          a0[m] = PKRTZ_U(s1[4 * m + 0], s1[4 * m + 1]);
          a1[m] = PKRTZ_U(s1[4 * m + 2], s1[4 * m + 3]);
        }
      }
      #pragma unroll
      for (int c = 0; c < 2; c++) {
        unsigned w0 = a0[2 * c], w2 = a0[2 * c + 1];
        unsigned w1 = a1[2 * c], w3 = a1[2 * c + 1];
        lane32swap(w0, w2);
        lane32swap(w1, w3);
        u32x4 t;
        t[0] = w0; t[1] = w1; t[2] = w2; t[3] = w3;
        pf[2 * T + c] = __builtin_bit_cast(half8, t);
      }
    }

    // ---- PV: O^T[d][q] += V^T[d][k] * P^T[k][q] ----
    __builtin_amdgcn_s_setprio(1);
    #pragma unroll
    for (int kc = 0; kc < 4; kc++)
      acc0 = __builtin_amdgcn_mfma_f32_32x32x16_f16(vf[0][kc], pf[kc], acc0, 0, 0, 0);
    #pragma unroll
    for (int kc = 0; kc < 4; kc++)
      acc1 = __builtin_amdgcn_mfma_f32_32x32x16_f16(vf[1][kc], pf[kc], acc1, 0, 0, 0);
    __builtin_amdgcn_s_setprio(0);

    __syncthreads();   // staged tiles landed (vmcnt drain); bufs ready
  }

  // ---- k-parity combine through LDS (reuses KV: 4 qsets x 2048 f32 = 32 KB) ----
  float* cacc = (float*)&KV[0][0];
  if (par == 1) {
    float* dst = cacc + qset * 2048;
    #pragma unroll
    for (int i = 0; i < 16; i++) {
      dst[i * 64 + lane] = acc0[i];
      dst[(16 + i) * 64 + lane] = acc1[i];
    }
    cml[qset][0][lane] = mi;
    cml[qset][1][lane] = li;
  }
  __syncthreads();
  if (par == 0) {
    const float mo = cml[qset][0][lane], lo2 = cml[qset][1][lane];
    const float* src = cacc + qset * 2048;
    const float M = fmaxf(mi, mo);
    const float we = EXP2(mi - M), wo = EXP2(mo - M);
    const float l = li * we + lo2 * wo;
    const float inv = (l > 0.f) ? 1.f / l : 0.f;
    if (direct) {
      float* orow = dsto + (size_t)(qrow0 + q31) * HID + h * HD;
      #pragma unroll
      for (int m = 0; m < 4; m++) {
        float4 v;
        v.x = (acc0[4 * m + 0] * we + src[(4 * m + 0) * 64 + lane] * wo) * inv;
        v.y = (acc0[4 * m + 1] * we + src[(4 * m + 1) * 64 + lane] * wo) * inv;
        v.z = (acc0[4 * m + 2] * we + src[(4 * m + 2) * 64 + lane] * wo) * inv;
        v.w = (acc0[4 * m + 3] * we + src[(4 * m + 3) * 64 + lane] * wo) * inv;
        *(float4*)&orow[8 * m + 4 * lh] = v;
      }
      #pragma unroll
      for (int m = 0; m < 4; m++) {
        float4 v;
        v.x = (acc1[4 * m + 0] * we + src[(16 + 4 * m + 0) * 64 + lane] * wo) * inv;
        v.y = (acc1[4 * m + 1] * we + src[(16 + 4 * m + 1) * 64 + lane] * wo) * inv;
        v.z = (acc1[4 * m + 2] * we + src[(16 + 4 * m + 2) * 64 + lane] * wo) * inv;
        v.w = (acc1[4 * m + 3] * we + src[(16 + 4 * m + 3) * 64 + lane] * wo) * inv;
        *(float4*)&orow[32 + 8 * m + 4 * lh] = v;
      }
    } else {
      const size_t rbase = ((size_t)z * NH + h) * S_LEN + qrow0 + q31;
      float* orow = dsto + rbase * HD;
      #pragma unroll
      for (int m = 0; m < 4; m++) {
        float4 v;
        v.x = (acc0[4 * m + 0] * we + src[(4 * m + 0) * 64 + lane] * wo) * inv;
        v.y = (acc0[4 * m + 1] * we + src[(4 * m + 1) * 64 + lane] * wo) * inv;
        v.z = (acc0[4 * m + 2] * we + src[(4 * m + 2) * 64 + lane] * wo) * inv;
        v.w = (acc0[4 * m + 3] * we + src[(4 * m + 3) * 64 + lane] * wo) * inv;
        *(float4*)&orow[8 * m + 4 * lh] = v;
      }
      #pragma unroll
      for (int m = 0; m < 4; m++) {
        float4 v;
        v.x = (acc1[4 * m + 0] * we + src[(16 + 4 * m + 0) * 64 + lane] * wo) * inv;
        v.y = (acc1[4 * m + 1] * we + src[(16 + 4 * m + 1) * 64 + lane] * wo) * inv;
        v.z = (acc1[4 * m + 2] * we + src[(16 + 4 * m + 2) * 64 + lane] * wo) * inv;
        v.w = (acc1[4 * m + 3] * we + src[(16 + 4 * m + 3) * 64 + lane] * wo) * inv;
        *(float4*)&orow[32 + 8 * m + 4 * lh] = v;
      }
      if (lane < 32) {
        ml[rbase * 2]     = M;
        ml[rbase * 2 + 1] = l;
      }
    }
  }
}

// ---------------- split-KV combine (log2-domain weights) ----------------
__global__ __launch_bounds__(256) void k_combine(const float* __restrict__ opart,
                                                 const float* __restrict__ ml,
                                                 float* __restrict__ out, int split) {
  const int gid = blockIdx.x * 256 + threadIdx.x;   // NH*S*16 threads
  const int row = gid >> 4;                          // h*S + q
  const int d0 = (gid & 15) << 2;
  const int h = row >> 12, q = row & (S_LEN - 1);
  float M = -INFINITY;
  for (int zz = 0; zz < split; zz++)
    M = fmaxf(M, ml[((size_t)zz * NH * S_LEN + row) * 2]);
  float wsum = 0.f;
  float o0 = 0.f, o1 = 0.f, o2 = 0.f, o3 = 0.f;
  for (int zz = 0; zz < split; zz++) {
    const size_t r = (size_t)zz * NH * S_LEN + row;
    float m = ml[r * 2], l = ml[r * 2 + 1];
    if (l > 0.f) {
      float w = l * EXP2(m - M);
      float4 v = *(const float4*)&opart[r * HD + d0];
      wsum += w;
      o0 += w * v.x; o1 += w * v.y; o2 += w * v.z; o3 += w * v.w;
    }
  }
  const float inv = (wsum > 0.f) ? (1.f / wsum) : 0.f;
  *(float4*)&out[(size_t)q * HID + h * HD + d0] =
      make_float4(o0 * inv, o1 * inv, o2 * inv, o3 * inv);
}

extern "C" void kernel_launch(void* const* d_in, const int* in_sizes, int n_in,
                              void* d_out, int out_size, void* d_ws, size_t ws_size,
                              hipStream_t stream) {
  const float* x    = (const float*)d_in[0];
  const float* mask = (const float*)d_in[1];
  const float* Wq   = (const float*)d_in[2];
  const float* bq   = (const float*)d_in[3];
  const float* Wk   = (const float*)d_in[4];
  const float* bk   = (const float*)d_in[5];
  const float* Wv   = (const float*)d_in[6];
  const float* bv   = (const float*)d_in[7];
  float* out = (float*)d_out;

  char* ws = (char*)d_ws;
  f16* xb  = (f16*)(ws);                       // 4096*768*2       = 6291456 B
  f16* wtb = (f16*)(ws + 6291456);             // 3*768*768*2      = 3538944 B
  f16* qbb = (f16*)(ws + 9830400);             // 12*4096*64*2     = 6291456 B
  f16* kbb = (f16*)(ws + 16121856);            // 6291456 B
  f16* vtb = (f16*)(ws + 22413312);            // 6291456 B  (end 28704768)
  float* mask2 = (float*)ws;                   // reuses xb space AFTER gemm is done

  const size_t base   = 28704768;
  const size_t o_per  = (size_t)NH * S_LEN * HD * 4;   // 12582912
  const size_t ml_per = (size_t)NH * S_LEN * 2 * 4;    // 393216

  int split = (ws_size >= base + 2 * (o_per + ml_per)) ? 2 : 1;

  k_convert_x<<<dim3(3072), dim3(256), 0, stream>>>(x, xb);
  k_transw<<<dim3(24, 24, 3), dim3(32, 8), 0, stream>>>(Wq, Wk, Wv, wtb);
  k_gemm_qkv<<<dim3(6, 32, 3), dim3(256), 0, stream>>>(xb, wtb, bq, bk, bv, qbb, kbb, vtb);
  k_maskcvt<<<dim3(4), dim3(256), 0, stream>>>(mask, mask2);   // xb dead after gemm

  if (split == 1) {
    // nkt = tiles per parity = 4096/64/2
    k_attn<<<dim3(32, NH, 1), dim3(512), 0, stream>>>(qbb, kbb, vtb, mask2, out, out,
                                                      S_LEN / 128, 1);
  } else {
    float* opart = (float*)(ws + base);
    float* mlb   = (float*)(ws + base + (size_t)split * o_per);
    k_attn<<<dim3(32, NH, split), dim3(512), 0, stream>>>(qbb, kbb, vtb, mask2, opart, mlb,
                                                          S_LEN / (128 * split), 0);
    k_combine<<<dim3(NH * S_LEN * 16 / 256), dim3(256), 0, stream>>>(opart, mlb, out, split);
  }
}